// Round 1
// baseline (1951.669 us; speedup 1.0000x reference)
//
#include <hip/hip_runtime.h>
#include <hip/hip_bf16.h>
#include <math.h>

// Problem constants (from reference)
#define B_   4
#define S_   4000
#define DIN  1024
#define DA   512
#define L_   8921

typedef __attribute__((ext_vector_type(8))) short    short8;  // 8 bf16 = 4 VGPRs (MFMA A/B frag)
typedef __attribute__((ext_vector_type(4))) float    f4;      // 4 f32 (MFMA C/D frag)
typedef __attribute__((ext_vector_type(4))) unsigned int u4;  // 16B vector for LDS/global moves

// f32 -> bf16 round-to-nearest-even (finite inputs only; fine here)
static __device__ __forceinline__ unsigned short f2b(float f) {
    unsigned int u = __float_as_uint(f);
    u += 0x7fffu + ((u >> 16) & 1u);
    return (unsigned short)(u >> 16);
}
static __device__ __forceinline__ unsigned int pack2(float lo, float hi) {
    return (unsigned int)f2b(lo) | ((unsigned int)f2b(hi) << 16);
}

// ---------------------------------------------------------------------------
// Kernel 1: z = tanh(x @ W^T + b)   [16000 x 512], output bf16 into ws
// 128x128 tile, BK=32, 4 waves in 2x2, each wave 64x64 (4x4 frags of 16x16x32)
// ---------------------------------------------------------------------------
__global__ __launch_bounds__(256) void k_z(const float* __restrict__ x,
                                           const float* __restrict__ Ww,
                                           const float* __restrict__ Wb,
                                           unsigned short* __restrict__ z)
{
    __shared__ unsigned short lds_a[128 * 32];
    __shared__ unsigned short lds_b[128 * 32];

    const int tid  = threadIdx.x;
    const int lane = tid & 63;
    const int w    = tid >> 6;
    const int wm   = w >> 1, wn = w & 1;
    const int q    = lane >> 4, r = lane & 15;
    const int m0   = blockIdx.x * 128;
    const int n0   = blockIdx.y * 128;

    f4 acc[4][4];
#pragma unroll
    for (int i = 0; i < 4; i++)
#pragma unroll
        for (int j = 0; j < 4; j++) { f4 zz = {0.f,0.f,0.f,0.f}; acc[i][j] = zz; }

    const int row  = tid >> 1;     // 0..127
    const int half = tid & 1;      // 16 f32 each

    for (int kk = 0; kk < DIN; kk += 32) {
        // A tile: x rows (M exact multiple of 128, no guard)
        {
            const f4* src = (const f4*)(x + (size_t)(m0 + row) * DIN + kk + half * 16);
            f4 v0 = src[0], v1 = src[1], v2 = src[2], v3 = src[3];
            u4* dst = (u4*)&lds_a[row * 32 + half * 16];
            u4 o0, o1;
            o0[0] = pack2(v0[0], v0[1]); o0[1] = pack2(v0[2], v0[3]);
            o0[2] = pack2(v1[0], v1[1]); o0[3] = pack2(v1[2], v1[3]);
            o1[0] = pack2(v2[0], v2[1]); o1[1] = pack2(v2[2], v2[3]);
            o1[2] = pack2(v3[0], v3[1]); o1[3] = pack2(v3[2], v3[3]);
            dst[0] = o0; dst[1] = o1;
        }
        // B tile: W rows (N = 512 exact, no guard)
        {
            const f4* src = (const f4*)(Ww + (size_t)(n0 + row) * DIN + kk + half * 16);
            f4 v0 = src[0], v1 = src[1], v2 = src[2], v3 = src[3];
            u4* dst = (u4*)&lds_b[row * 32 + half * 16];
            u4 o0, o1;
            o0[0] = pack2(v0[0], v0[1]); o0[1] = pack2(v0[2], v0[3]);
            o0[2] = pack2(v1[0], v1[1]); o0[3] = pack2(v1[2], v1[3]);
            o1[0] = pack2(v2[0], v2[1]); o1[1] = pack2(v2[2], v2[3]);
            o1[2] = pack2(v3[0], v3[1]); o1[3] = pack2(v3[2], v3[3]);
            dst[0] = o0; dst[1] = o1;
        }
        __syncthreads();

        short8 af[4], bfr[4];
#pragma unroll
        for (int i = 0; i < 4; i++) {
            af[i]  = *(const short8*)&lds_a[(wm * 64 + i * 16 + r) * 32 + q * 8];
            bfr[i] = *(const short8*)&lds_b[(wn * 64 + i * 16 + r) * 32 + q * 8];
        }
#pragma unroll
        for (int i = 0; i < 4; i++)
#pragma unroll
            for (int j = 0; j < 4; j++)
                acc[i][j] = __builtin_amdgcn_mfma_f32_16x16x32_bf16(af[i], bfr[j], acc[i][j], 0, 0, 0);
        __syncthreads();
    }

    // epilogue: tanh(acc + bias) -> bf16 z
#pragma unroll
    for (int i = 0; i < 4; i++) {
#pragma unroll
        for (int j = 0; j < 4; j++) {
            const int col = n0 + wn * 64 + j * 16 + r;
            const float bias = Wb[col];
#pragma unroll
            for (int e = 0; e < 4; e++) {
                const int rowg = m0 + wm * 64 + i * 16 + q * 4 + e;
                z[(size_t)rowg * DA + col] = f2b(tanhf(acc[i][j][e] + bias));
            }
        }
    }
}

// ---------------------------------------------------------------------------
// Kernel 2: scores[b,l,s] = U[l,:] . z[b,s,:]   -> f32 into alpha region of d_out
// M=L (8921), N=S (4000), K=DA (512). Same 128x128 structure.
// ---------------------------------------------------------------------------
__global__ __launch_bounds__(256) void k_scores(const float* __restrict__ U,
                                                const unsigned short* __restrict__ z,
                                                float* __restrict__ out)
{
    __shared__ unsigned short lds_a[128 * 32];
    __shared__ unsigned short lds_b[128 * 32];

    const int tid  = threadIdx.x;
    const int lane = tid & 63;
    const int w    = tid >> 6;
    const int wm   = w >> 1, wn = w & 1;
    const int q    = lane >> 4, r = lane & 15;
    const int b    = blockIdx.z;
    const int m0   = blockIdx.x * 128;
    const int n0   = blockIdx.y * 128;

    f4 acc[4][4];
#pragma unroll
    for (int i = 0; i < 4; i++)
#pragma unroll
        for (int j = 0; j < 4; j++) { f4 zz = {0.f,0.f,0.f,0.f}; acc[i][j] = zz; }

    const int row  = tid >> 1;   // 0..127 (A staging: f32 -> bf16)
    const int half = tid & 1;
    const int brow = tid >> 2;   // 0..63  (B staging: bf16 passthrough)
    const int bseg = tid & 3;

    for (int kk = 0; kk < DA; kk += 32) {
        // A tile: U rows (guard M edge)
        {
            u4* dst = (u4*)&lds_a[row * 32 + half * 16];
            const int gm = m0 + row;
            if (gm < L_) {
                const f4* src = (const f4*)(U + (size_t)gm * DA + kk + half * 16);
                f4 v0 = src[0], v1 = src[1], v2 = src[2], v3 = src[3];
                u4 o0, o1;
                o0[0] = pack2(v0[0], v0[1]); o0[1] = pack2(v0[2], v0[3]);
                o0[2] = pack2(v1[0], v1[1]); o0[3] = pack2(v1[2], v1[3]);
                o1[0] = pack2(v2[0], v2[1]); o1[1] = pack2(v2[2], v2[3]);
                o1[2] = pack2(v3[0], v3[1]); o1[3] = pack2(v3[2], v3[3]);
                dst[0] = o0; dst[1] = o1;
            } else {
                u4 zz = {0,0,0,0}; dst[0] = zz; dst[1] = zz;
            }
        }
        // B tile: z rows for this batch (guard N edge at s=4000)
#pragma unroll
        for (int jj = 0; jj < 2; jj++) {
            const int rr = brow + jj * 64;
            const int gs = n0 + rr;
            u4* dst = (u4*)&lds_b[rr * 32 + bseg * 8];
            if (gs < S_) {
                *dst = *(const u4*)&z[((size_t)(b * S_ + gs)) * DA + kk + bseg * 8];
            } else {
                u4 zz = {0,0,0,0}; *dst = zz;
            }
        }
        __syncthreads();

        short8 af[4], bfr[4];
#pragma unroll
        for (int i = 0; i < 4; i++) {
            af[i]  = *(const short8*)&lds_a[(wm * 64 + i * 16 + r) * 32 + q * 8];
            bfr[i] = *(const short8*)&lds_b[(wn * 64 + i * 16 + r) * 32 + q * 8];
        }
#pragma unroll
        for (int i = 0; i < 4; i++)
#pragma unroll
            for (int j = 0; j < 4; j++)
                acc[i][j] = __builtin_amdgcn_mfma_f32_16x16x32_bf16(af[i], bfr[j], acc[i][j], 0, 0, 0);
        __syncthreads();
    }

#pragma unroll
    for (int i = 0; i < 4; i++) {
#pragma unroll
        for (int j = 0; j < 4; j++) {
            const int colg = n0 + wn * 64 + j * 16 + r;
#pragma unroll
            for (int e = 0; e < 4; e++) {
                const int rowg = m0 + wm * 64 + i * 16 + q * 4 + e;
                if (rowg < L_ && colg < S_)
                    out[((size_t)b * L_ + rowg) * S_ + colg] = acc[i][j][e];
            }
        }
    }
}

// ---------------------------------------------------------------------------
// Kernel 3: in-place softmax over each row of 4000 (grid = B*L rows)
// ---------------------------------------------------------------------------
__global__ __launch_bounds__(256) void k_softmax(float* __restrict__ a)
{
    float* p = a + (size_t)blockIdx.x * S_;
    const int tid = threadIdx.x;

    f4 v[4];
    float mx = -3.4e38f;
#pragma unroll
    for (int j = 0; j < 4; j++) {
        const int vi = tid + j * 256;
        if (vi < S_ / 4) {
            v[j] = ((const f4*)p)[vi];
            mx = fmaxf(mx, fmaxf(fmaxf(v[j][0], v[j][1]), fmaxf(v[j][2], v[j][3])));
        }
    }
#pragma unroll
    for (int off = 32; off > 0; off >>= 1) mx = fmaxf(mx, __shfl_xor(mx, off, 64));

    __shared__ float red[8];
    if ((tid & 63) == 0) red[tid >> 6] = mx;
    __syncthreads();
    mx = fmaxf(fmaxf(red[0], red[1]), fmaxf(red[2], red[3]));

    float s = 0.f;
#pragma unroll
    for (int j = 0; j < 4; j++) {
        const int vi = tid + j * 256;
        if (vi < S_ / 4) {
#pragma unroll
            for (int c = 0; c < 4; c++) { v[j][c] = __expf(v[j][c] - mx); s += v[j][c]; }
        }
    }
#pragma unroll
    for (int off = 32; off > 0; off >>= 1) s += __shfl_xor(s, off, 64);
    if ((tid & 63) == 0) red[4 + (tid >> 6)] = s;
    __syncthreads();
    s = red[4] + red[5] + red[6] + red[7];

    const float inv = 1.f / s;
#pragma unroll
    for (int j = 0; j < 4; j++) {
        const int vi = tid + j * 256;
        if (vi < S_ / 4) {
            f4 o = v[j]; o[0] *= inv; o[1] *= inv; o[2] *= inv; o[3] *= inv;
            ((f4*)p)[vi] = o;
        }
    }
}

// ---------------------------------------------------------------------------
// Kernel 4: transpose z [b,s,a] -> zT [b,a,s]  (bf16, 32x32 LDS tiles)
// ---------------------------------------------------------------------------
__global__ __launch_bounds__(256) void k_transpose(const unsigned short* __restrict__ z,
                                                   unsigned short* __restrict__ zT)
{
    __shared__ unsigned short t[32][33];
    const int b  = blockIdx.z;
    const int s0 = blockIdx.x * 32;
    const int a0 = blockIdx.y * 32;
    const int c  = threadIdx.x & 31;
    const int r4 = threadIdx.x >> 5;   // 0..7

#pragma unroll
    for (int i = 0; i < 4; i++) {
        const int sl = r4 * 4 + i;
        t[sl][c] = z[((size_t)(b * S_ + s0 + sl)) * DA + a0 + c];
    }
    __syncthreads();
#pragma unroll
    for (int i = 0; i < 4; i++) {
        const int al = r4 * 4 + i;
        zT[((size_t)(b * DA + a0 + al)) * S_ + s0 + c] = t[c][al];
    }
}

// ---------------------------------------------------------------------------
// Kernel 5: m = alpha @ z (per batch) fused with y = V.m + Vb
// Tile: M=64 labels x N=512 (full DA), K=S (4000). 4 waves, wave w -> cols w*128..+128
// ---------------------------------------------------------------------------
__global__ __launch_bounds__(256) void k_mv(const float* __restrict__ alpha,
                                            const unsigned short* __restrict__ zT,
                                            const float* __restrict__ Vw,
                                            const float* __restrict__ Vb,
                                            float* __restrict__ y)
{
    __shared__ unsigned short lds_a[64 * 32];
    __shared__ unsigned short lds_b[512 * 32];
    __shared__ float yred[64];

    const int tid  = threadIdx.x;
    const int lane = tid & 63;
    const int w    = tid >> 6;
    const int q    = lane >> 4, r = lane & 15;
    const int b    = blockIdx.y;
    const int m0   = blockIdx.x * 64;

    if (tid < 64) yred[tid] = 0.f;

    f4 acc[4][8];
#pragma unroll
    for (int i = 0; i < 4; i++)
#pragma unroll
        for (int j = 0; j < 8; j++) { f4 zz = {0.f,0.f,0.f,0.f}; acc[i][j] = zz; }

    const int arow = tid >> 2;  // 0..63
    const int aseg = tid & 3;   // 8 elems each

    for (int kk = 0; kk < S_; kk += 32) {
        // A tile: alpha rows, f32 -> bf16 (guard M edge)
        {
            u4* dst = (u4*)&lds_a[arow * 32 + aseg * 8];
            const int gl = m0 + arow;
            if (gl < L_) {
                const f4* src = (const f4*)(alpha + ((size_t)b * L_ + gl) * S_ + kk + aseg * 8);
                f4 v0 = src[0], v1 = src[1];
                u4 o;
                o[0] = pack2(v0[0], v0[1]); o[1] = pack2(v0[2], v0[3]);
                o[2] = pack2(v1[0], v1[1]); o[3] = pack2(v1[2], v1[3]);
                *dst = o;
            } else {
                u4 zz = {0,0,0,0}; *dst = zz;
            }
        }
        // B tile: zT rows 0..511 (bf16 passthrough)
#pragma unroll
        for (int jj = 0; jj < 8; jj++) {
            const int rr = arow + jj * 64;
            *(u4*)&lds_b[rr * 32 + aseg * 8] =
                *(const u4*)&zT[((size_t)(b * DA + rr)) * S_ + kk + aseg * 8];
        }
        __syncthreads();

        short8 af[4], bfr[8];
#pragma unroll
        for (int i = 0; i < 4; i++)
            af[i] = *(const short8*)&lds_a[(i * 16 + r) * 32 + q * 8];
#pragma unroll
        for (int j = 0; j < 8; j++)
            bfr[j] = *(const short8*)&lds_b[(w * 128 + j * 16 + r) * 32 + q * 8];
#pragma unroll
        for (int i = 0; i < 4; i++)
#pragma unroll
            for (int j = 0; j < 8; j++)
                acc[i][j] = __builtin_amdgcn_mfma_f32_16x16x32_bf16(af[i], bfr[j], acc[i][j], 0, 0, 0);
        __syncthreads();
    }

    // epilogue: y[l] += sum_a m[l,a] * V[l,a]
#pragma unroll
    for (int i = 0; i < 4; i++) {
#pragma unroll
        for (int e = 0; e < 4; e++) {
            const int rowl = i * 16 + q * 4 + e;
            const int gl = m0 + rowl;
            if (gl < L_) {
                float p = 0.f;
#pragma unroll
                for (int j = 0; j < 8; j++) {
                    const int col = w * 128 + j * 16 + r;
                    p += acc[i][j][e] * Vw[(size_t)gl * DA + col];
                }
                atomicAdd(&yred[rowl], p);
            }
        }
    }
    __syncthreads();
    if (tid < 64 && (m0 + tid) < L_)
        y[b * L_ + m0 + tid] = yred[tid] + Vb[m0 + tid];
}

// ---------------------------------------------------------------------------
extern "C" void kernel_launch(void* const* d_in, const int* in_sizes, int n_in,
                              void* d_out, int out_size, void* d_ws, size_t ws_size,
                              hipStream_t stream)
{
    const float* x  = (const float*)d_in[0];
    const float* Ww = (const float*)d_in[1];
    const float* Wb = (const float*)d_in[2];
    const float* Uw = (const float*)d_in[3];
    const float* Vw = (const float*)d_in[4];
    const float* Vb = (const float*)d_in[5];

    float* y     = (float*)d_out;
    float* alpha = y + (size_t)B_ * L_;   // outputs concatenated: y then alpha

    unsigned short* z  = (unsigned short*)d_ws;               // [B*S, DA] bf16
    unsigned short* zT = z + (size_t)B_ * S_ * DA;            // [B, DA, S] bf16

    k_z<<<dim3(125, 4), dim3(256), 0, stream>>>(x, Ww, Wb, z);
    k_scores<<<dim3(70, 32, B_), dim3(256), 0, stream>>>(Uw, z, alpha);
    k_softmax<<<dim3(B_ * L_), dim3(256), 0, stream>>>(alpha);
    k_transpose<<<dim3(125, 16, B_), dim3(256), 0, stream>>>(z, zT);
    k_mv<<<dim3(140, B_), dim3(256), 0, stream>>>(alpha, zT, Vw, Vb, y);
}